// Round 19
// baseline (543.773 us; speedup 1.0000x reference)
//
#include <hip/hip_runtime.h>
#include <hip/hip_bf16.h>

typedef __attribute__((ext_vector_type(8))) short short8;
typedef __attribute__((ext_vector_type(4))) float f32x4;
typedef __attribute__((ext_vector_type(16))) float f32x16;

#define GLD16(gp, lp) __builtin_amdgcn_global_load_lds( \
    (const __attribute__((address_space(1))) unsigned int*)(gp), \
    (__attribute__((address_space(3))) unsigned int*)(lp), 16, 0, 0)

static __device__ __forceinline__ float bf2f(unsigned short u) {
    union { unsigned int i; float f; } v; v.i = ((unsigned int)u) << 16; return v.f;
}
static __device__ __forceinline__ short f2bf(float f) {
    union { float f; unsigned int i; } v; v.f = f;
    unsigned int r = v.i + 0x7FFFu + ((v.i >> 16) & 1u);
    return (short)(r >> 16);
}
static __device__ __forceinline__ unsigned int cvtpk(float lo, float hi) {
    unsigned int w;
    asm("v_cvt_pk_bf16_f32 %0, %1, %2" : "=v"(w) : "v"(lo), "v"(hi));
    return w;
}

// ---------------- elementwise cast fp32 -> bf16 ----------------
__global__ void cast_f32_bf16(const float* __restrict__ src, short* __restrict__ dst, int n) {
    int i = (blockIdx.x * 256 + threadIdx.x) * 4;
    if (i >= n) return;
    float4 v = *(const float4*)(src + i);
    short4 o;
    o.x = f2bf(v.x); o.y = f2bf(v.y); o.z = f2bf(v.z); o.w = f2bf(v.w);
    *(short4*)(dst + i) = o;
}

// ---------------- merged transpose+cast for wq/wk/wv -> wt_qkv (6144 x 4096 bf16) ----------------
__global__ void transpose_cast_qkv(const float* __restrict__ wq, const float* __restrict__ wk,
                                   const float* __restrict__ wv, short* __restrict__ dst) {
    __shared__ float tile[32][33];
    int k0 = blockIdx.x * 32;
    int yt = blockIdx.y;
    const float* src;
    int N, n0, rowbase;
    if (yt < 128)      { src = wq; N = 4096; n0 = yt * 32;         rowbase = n0; }
    else if (yt < 160) { src = wk; N = 1024; n0 = (yt - 128) * 32; rowbase = 4096 + n0; }
    else               { src = wv; N = 1024; n0 = (yt - 160) * 32; rowbase = 5120 + n0; }
    int t = threadIdx.x, c = t & 31, r = t >> 5;
#pragma unroll
    for (int p = 0; p < 4; ++p)
        tile[r + p * 8][c] = src[(size_t)(k0 + r + p * 8) * N + n0 + c];
    __syncthreads();
#pragma unroll
    for (int p = 0; p < 4; ++p)
        dst[(size_t)(rowbase + r + p * 8) * 4096 + k0 + c] = f2bf(tile[c][r + p * 8]);
}

// ---------------- transpose+cast: src fp32 (K x N) -> dst bf16 (N x K) ----------------
__global__ void transpose_cast(const float* __restrict__ src, short* __restrict__ dst,
                               int N, int dstStride) {
    __shared__ float tile[32][33];
    int k0 = blockIdx.x * 32, n0 = blockIdx.y * 32;
    int t = threadIdx.x, c = t & 31, r = t >> 5;
#pragma unroll
    for (int p = 0; p < 4; ++p)
        tile[r + p * 8][c] = src[(size_t)(k0 + r + p * 8) * N + n0 + c];
    __syncthreads();
#pragma unroll
    for (int p = 0; p < 4; ++p)
        dst[(size_t)(n0 + r + p * 8) * dstStride + k0 + c] = f2bf(tile[c][r + p * 8]);
}

// ---------------- rope tables: [2048][64] float2 (cos,sin) ----------------
__global__ void rope_tables(float* __restrict__ cs) {
    int i = blockIdx.x * 256 + threadIdx.x;
    int s = i >> 6, d2 = i & 63;
    float inv = expf(-9.210340371976184f * (float)(2 * d2) * (1.0f / 128.0f));
    float ang = (float)s * inv;
    float sn, c;
    sincosf(ang, &sn, &c);
    cs[(size_t)i * 2] = c;
    cs[(size_t)i * 2 + 1] = sn;
}

// ---------------- QKV GEMM 128x128 + FUSED rope/regroup/V-transpose epilogue (frozen) ----------------
__global__ __launch_bounds__(256, 2) void gemm_qkv(const short* __restrict__ A,
                                                   const short* __restrict__ Bt,
                                                   short* __restrict__ Qr,
                                                   short* __restrict__ Kr,
                                                   short* __restrict__ Vt,
                                                   const float* __restrict__ tab) {
    __shared__ short As[128 * 64];
    __shared__ short Bs[128 * 64];
    const int K = 4096;
    const int tid = threadIdx.x;
    const int lane = tid & 63;
    const int wid = tid >> 6;
    const int lr = lane & 15;
    const int lq = lane >> 4;
    const int m0 = blockIdx.x * 128;
    const int n0 = blockIdx.y * 128;
    const int wr = (wid >> 1) * 64;
    const int wc = (wid & 1) * 64;
    f32x4 acc[4][4];
#pragma unroll
    for (int i = 0; i < 4; ++i)
#pragma unroll
        for (int j = 0; j < 4; ++j) acc[i][j] = f32x4{0.f, 0.f, 0.f, 0.f};

    const short* aBase = A + (size_t)m0 * K;
    const short* bBase = Bt + (size_t)n0 * K;

    for (int k0 = 0; k0 < K; k0 += 64) {
#pragma unroll
        for (int j = 0; j < 4; ++j) {
            int c = (wid * 4 + j) * 64 + lane;
            int row = c >> 3;
            int cb = ((c & 7) << 4) ^ ((row & 7) << 4);
            GLD16(aBase + (size_t)row * K + k0 + (cb >> 1), As + (wid * 4 + j) * 512);
            GLD16(bBase + (size_t)row * K + k0 + (cb >> 1), Bs + (wid * 4 + j) * 512);
        }
        __syncthreads();
#pragma unroll
        for (int ks = 0; ks < 2; ++ks) {
            short8 af[4], bfr[4];
#pragma unroll
            for (int mi = 0; mi < 4; ++mi) {
                int row = wr + mi * 16 + lr;
                int cb = (ks * 64 + lq * 16) ^ ((row & 7) << 4);
                af[mi] = *(const short8*)(As + row * 64 + (cb >> 1));
            }
#pragma unroll
            for (int ni = 0; ni < 4; ++ni) {
                int row = wc + ni * 16 + lr;
                int cb = (ks * 64 + lq * 16) ^ ((row & 7) << 4);
                bfr[ni] = *(const short8*)(Bs + row * 64 + (cb >> 1));
            }
#pragma unroll
            for (int mi = 0; mi < 4; ++mi)
#pragma unroll
                for (int ni = 0; ni < 4; ++ni)
                    acc[mi][ni] = __builtin_amdgcn_mfma_f32_16x16x32_bf16(af[mi], bfr[ni], acc[mi][ni], 0, 0, 0);
        }
        __syncthreads();
    }

    const float2* t2 = (const float2*)tab;
    if (n0 < 5120) {
        const bool isQ = (n0 < 4096);
        short* dst = isQ ? Qr : Kr;
        const int nh = isQ ? 32 : 8;
        const int coff = isQ ? 0 : 4096;
        const float sc = isQ ? 0.1275174358f : 1.0f;   // (1/sqrt(128)) * log2(e) for Q
#pragma unroll
        for (int mi = 0; mi < 4; ++mi)
#pragma unroll
            for (int ni = 0; ni < 4; ++ni) {
                int col = n0 + wc + ni * 16 + lr - coff;
                int h = col >> 7;
                int d = col & 127;
                int d2 = d >> 1;
                const bool odd = d & 1;
#pragma unroll
                for (int r = 0; r < 4; ++r) {
                    int row = m0 + wr + mi * 16 + lq * 4 + r;
                    int s = row & 2047;
                    int b = row >> 11;
                    float v = acc[mi][ni][r];
                    float vp = __shfl_xor(v, 1, 64);
                    float2 cs2 = t2[s * 64 + d2];
                    float o = odd ? (v * cs2.x + vp * cs2.y) : (v * cs2.x - vp * cs2.y);
                    dst[((size_t)(b * nh + h) * 2048 + s) * 128 + d] = f2bf(o * sc);
                }
            }
    } else {
#pragma unroll
        for (int mi = 0; mi < 4; ++mi)
#pragma unroll
            for (int ni = 0; ni < 4; ++ni) {
                int col = n0 + wc + ni * 16 + lr - 5120;
                int h = col >> 7;
                int d = col & 127;
                int row0 = m0 + wr + mi * 16 + lq * 4;
                int s0 = row0 & 2047;
                int b = row0 >> 11;
                short4 o4;
                o4.x = f2bf(acc[mi][ni][0]);
                o4.y = f2bf(acc[mi][ni][1]);
                o4.z = f2bf(acc[mi][ni][2]);
                o4.w = f2bf(acc[mi][ni][3]);
                *(short4*)(Vt + (size_t)(b * 8 + h) * 128 * 2048 + (size_t)d * 2048 + s0) = o4;
            }
    }
}

// ---------------- GEMM 128x128 (r3-exact, measured-best WO) ----------------
template<bool BF16OUT>
__global__ __launch_bounds__(256, 2) void gemm_bt(const short* __restrict__ A,
                                                  const short* __restrict__ Bt,
                                                  void* __restrict__ Cv,
                                                  int N, int K) {
    __shared__ short As[128 * 64];
    __shared__ short Bs[128 * 64];
    const int tid = threadIdx.x;
    const int lane = tid & 63;
    const int wid = tid >> 6;
    const int lr = lane & 15;
    const int lq = lane >> 4;
    const int m0 = blockIdx.x * 128;
    const int n0 = blockIdx.y * 128;
    const int wr = (wid >> 1) * 64;
    const int wc = (wid & 1) * 64;
    f32x4 acc[4][4];
#pragma unroll
    for (int i = 0; i < 4; ++i)
#pragma unroll
        for (int j = 0; j < 4; ++j) acc[i][j] = f32x4{0.f, 0.f, 0.f, 0.f};

    const short* aBase = A + (size_t)m0 * K;
    const short* bBase = Bt + (size_t)n0 * K;

    for (int k0 = 0; k0 < K; k0 += 64) {
#pragma unroll
        for (int j = 0; j < 4; ++j) {
            int c = (wid * 4 + j) * 64 + lane;
            int row = c >> 3;
            int cb = ((c & 7) << 4) ^ ((row & 7) << 4);
            GLD16(aBase + (size_t)row * K + k0 + (cb >> 1), As + (wid * 4 + j) * 512);
            GLD16(bBase + (size_t)row * K + k0 + (cb >> 1), Bs + (wid * 4 + j) * 512);
        }
        __syncthreads();
#pragma unroll
        for (int ks = 0; ks < 2; ++ks) {
            short8 af[4], bfr[4];
#pragma unroll
            for (int mi = 0; mi < 4; ++mi) {
                int row = wr + mi * 16 + lr;
                int cb = (ks * 64 + lq * 16) ^ ((row & 7) << 4);
                af[mi] = *(const short8*)(As + row * 64 + (cb >> 1));
            }
#pragma unroll
            for (int ni = 0; ni < 4; ++ni) {
                int row = wc + ni * 16 + lr;
                int cb = (ks * 64 + lq * 16) ^ ((row & 7) << 4);
                bfr[ni] = *(const short8*)(Bs + row * 64 + (cb >> 1));
            }
#pragma unroll
            for (int mi = 0; mi < 4; ++mi)
#pragma unroll
                for (int ni = 0; ni < 4; ++ni)
                    acc[mi][ni] = __builtin_amdgcn_mfma_f32_16x16x32_bf16(af[mi], bfr[ni], acc[mi][ni], 0, 0, 0);
        }
        __syncthreads();
    }
#pragma unroll
    for (int mi = 0; mi < 4; ++mi)
#pragma unroll
        for (int ni = 0; ni < 4; ++ni)
#pragma unroll
            for (int r = 0; r < 4; ++r) {
                int row = m0 + wr + mi * 16 + lq * 4 + r;
                int col = n0 + wc + ni * 16 + lr;
                float v = acc[mi][ni][r];
                if constexpr (BF16OUT) ((short*)Cv)[(size_t)row * N + col] = f2bf(v);
                else                   ((float*)Cv)[(size_t)row * N + col] = v;
            }
}

// ---------------- flash attention v9: 8 waves (QBLK=256), BALANCED + XCD-affine + exp2 ----------------
// Body = r15's verified v7 (8-wave, dbuf K/V, vmcnt(4), in-register P). NEW mapping combines
// r16's complementary balance with affinity: 512 blocks, 2 rounds; blocks id and id+256 (same CU
// slot) get qb = {7-q̂, q̂} -> per-CU total EXACTLY 36 iterations (r15's failure was 2 equal-qb
// blocks/CU -> Occ 13%). 2 blocks x 8 waves = 16 waves/CU = 4 waves/SIMD (2x r16's TLP against
// the serial QK->softmax->PV chain). KV group g = xcd + 8*(slot>>4): L2-resident, 2 groups/XCD.
__global__ __launch_bounds__(512, 2) void attn_kernel(const short* __restrict__ Qr,
                                                      const short* __restrict__ Kr,
                                                      const short* __restrict__ Vt,
                                                      short* __restrict__ Out) {
    __shared__ short kv[4 * 8192];   // [buf][Ks 8192 | Vs 8192] shorts
    const int id = blockIdx.x;       // 0..511
    const int rnd = id >> 8;         // 0..1
    const int low = id & 255;
    const int xcd = low & 7;
    const int slot = low >> 3;       // 0..31
    const int g = xcd + 8 * (slot >> 4);   // KV group 0..15
    const int b = g >> 3;
    const int kvh = g & 7;
    const int s16 = slot & 15;
    const int qh = kvh * 4 + (s16 & 3);
    const int qbase = s16 >> 2;      // 0..3
    const int qb = rnd == 0 ? 7 - qbase : qbase;   // rounds partition qb 0..7; pairs sum to 7
    const int bh = b * 32 + qh;
    const int tid = threadIdx.x;     // 0..511
    const int lane = tid & 63;
    const int w = tid >> 6;          // 0..7
    const int l31 = lane & 31;
    const int hi = lane >> 5;
    const int qg0 = qb * 256 + w * 32;

    const short* qbase_p = Qr + ((size_t)bh * 2048 + qg0 + l31) * 128 + hi * 8;
    short8 qf[8];
#pragma unroll
    for (int ks = 0; ks < 8; ++ks)
        qf[ks] = *(const short8*)(qbase_p + ks * 16);

    const short* kbase = Kr + (size_t)(b * 8 + kvh) * 2048 * 128;
    const short* vbase = Vt + (size_t)(b * 8 + kvh) * 128 * 2048;

    auto stage = [&](int kb, int buf) {
        const int s0 = kb * 64;
        short* Kd = kv + buf * 16384;
        short* Vd = kv + buf * 16384 + 8192;
#pragma unroll
        for (int j = 0; j < 2; ++j) {
            int c = j * 512 + tid;             // 0..1023
            int krow = c >> 4;
            int kcol = ((c & 15) ^ (krow & 7)) * 8;
            GLD16(kbase + (size_t)(s0 + krow) * 128 + kcol, Kd + (size_t)c * 8);
            int vrow = c >> 3;
            int vcol = ((c & 7) ^ (vrow & 7)) * 8;
            GLD16(vbase + (size_t)vrow * 2048 + s0 + vcol, Vd + (size_t)c * 8);
        }
    };

    float m_run = -INFINITY, l_run = 0.0f;
    f32x16 oacc[4];
#pragma unroll
    for (int dt = 0; dt < 4; ++dt) oacc[dt] = f32x16{0,0,0,0,0,0,0,0,0,0,0,0,0,0,0,0};

    const int nkb = 4 * qb + 4;
    stage(0, 0);   // prologue

    for (int kb = 0; kb < nkb; ++kb) {
        const int buf = kb & 1;
        const int s0 = kb * 64;
        const short* Ks = kv + buf * 16384;
        const short* Vs = kv + buf * 16384 + 8192;

        if (kb + 1 < nkb) {
            stage(kb + 1, buf ^ 1);
            __builtin_amdgcn_sched_barrier(0);
            asm volatile("s_waitcnt vmcnt(4)" ::: "memory");   // stage(kb) landed; prefetch in flight
        } else {
            asm volatile("s_waitcnt vmcnt(0)" ::: "memory");
        }
        __builtin_amdgcn_sched_barrier(0);
        __builtin_amdgcn_s_barrier();
        __builtin_amdgcn_sched_barrier(0);

        if (s0 <= qg0 + 31) {
            f32x16 st0 = f32x16{0,0,0,0,0,0,0,0,0,0,0,0,0,0,0,0};
            f32x16 st1 = f32x16{0,0,0,0,0,0,0,0,0,0,0,0,0,0,0,0};
            __builtin_amdgcn_s_setprio(1);
#pragma unroll
            for (int ks = 0; ks < 8; ++ks) {
                int row0 = l31;
                int ch0 = ((2 * ks + hi) ^ (row0 & 7)) * 8;
                short8 kf0 = *(const short8*)(Ks + row0 * 128 + ch0);
                st0 = __builtin_amdgcn_mfma_f32_32x32x16_bf16(kf0, qf[ks], st0, 0, 0, 0);
                int row1 = 32 + l31;
                int ch1 = ((2 * ks + hi) ^ (row1 & 7)) * 8;
                short8 kf1 = *(const short8*)(Ks + row1 * 128 + ch1);
                st1 = __builtin_amdgcn_mfma_f32_32x32x16_bf16(kf1, qf[ks], st1, 0, 0, 0);
            }
            __builtin_amdgcn_s_setprio(0);

            const int q = qg0 + l31;
            if (s0 + 63 > qg0) {
#pragma unroll
                for (int i = 0; i < 16; ++i) {
                    int kvr = (i & 3) + 8 * (i >> 2) + 4 * hi;
                    if (s0 + kvr > q)      st0[i] = -INFINITY;
                    if (s0 + 32 + kvr > q) st1[i] = -INFINITY;
                }
            }

            float mx = -INFINITY;
#pragma unroll
            for (int i = 0; i < 16; ++i) mx = fmaxf(mx, fmaxf(st0[i], st1[i]));
            mx = fmaxf(mx, __shfl_xor(mx, 32, 64));

            const bool defer = __all(mx - m_run <= 11.5415603f);   // 8 * log2(e)
            float mN, alpha;
            if (defer) { mN = m_run; alpha = 1.0f; }
            else       { mN = fmaxf(m_run, mx); alpha = exp2f(m_run - mN); }

            float p0[16], p1[16];
            float rsum = 0.0f;
#pragma unroll
            for (int i = 0; i < 16; ++i) {
                p0[i] = exp2f(st0[i] - mN);
                p1[i] = exp2f(st1[i] - mN);
                rsum += p0[i] + p1[i];
            }
            rsum += __shfl_xor(rsum, 32, 64);
            l_run = l_run * alpha + rsum;
            m_run = mN;
            if (!defer) {
#pragma unroll
                for (int dt = 0; dt < 4; ++dt)
#pragma unroll
                    for (int i = 0; i < 16; ++i) oacc[dt][i] *= alpha;
            }

            short8 pfr[4];
#pragma unroll
            for (int kvs = 0; kvs < 4; ++kvs) {
                const float* pp = (kvs < 2) ? p0 : p1;
                const int h8 = (kvs & 1) * 8;
                unsigned int x0 = cvtpk(pp[h8 + 0], pp[h8 + 1]);
                unsigned int x1 = cvtpk(pp[h8 + 2], pp[h8 + 3]);
                unsigned int y0 = cvtpk(pp[h8 + 4], pp[h8 + 5]);
                unsigned int y1 = cvtpk(pp[h8 + 6], pp[h8 + 7]);
                asm("v_permlane32_swap_b32 %0, %1" : "+v"(x0), "+v"(y0));
                asm("v_permlane32_swap_b32 %0, %1" : "+v"(x1), "+v"(y1));
                union { unsigned int u[4]; short8 s; } uu;
                uu.u[0] = x0; uu.u[1] = x1; uu.u[2] = y0; uu.u[3] = y1;
                pfr[kvs] = uu.s;
            }

            __builtin_amdgcn_s_setprio(1);
#pragma unroll
            for (int dt = 0; dt < 4; ++dt) {
                int row = dt * 32 + l31;
#pragma unroll
                for (int kvs = 0; kvs < 4; ++kvs) {
                    int ch = ((2 * kvs + hi) ^ (row & 7)) * 8;
                    short8 vf = *(const short8*)(Vs + row * 64 + ch);
                    oacc[dt] = __builtin_amdgcn_mfma_f32_32x32x16_bf16(vf, pfr[kvs], oacc[dt], 0, 0, 0);
                }
            }
            __builtin_amdgcn_s_setprio(0);
        }
        __builtin_amdgcn_sched_barrier(0);
        __builtin_amdgcn_s_barrier();
        __builtin_amdgcn_sched_barrier(0);
    }

    const float inv = 1.0f / l_run;
    const size_t row = (size_t)b * 2048 + qg0 + l31;
    short* obase = Out + row * 4096 + qh * 128;
#pragma unroll
    for (int dt = 0; dt < 4; ++dt) {
#pragma unroll
        for (int g2 = 0; g2 < 4; ++g2) {
            short4 o4;
            o4.x = f2bf(oacc[dt][g2 * 4 + 0] * inv);
            o4.y = f2bf(oacc[dt][g2 * 4 + 1] * inv);
            o4.z = f2bf(oacc[dt][g2 * 4 + 2] * inv);
            o4.w = f2bf(oacc[dt][g2 * 4 + 3] * inv);
            *(short4*)(obase + dt * 32 + g2 * 8 + hi * 4) = o4;
        }
    }
}

// ---------------- workspace layout (bytes) ----------------
// WT_QKV  @ 0          : 6144x4096 bf16 = 50331648
// XB      @ 50331648   : 4096x4096 bf16 = 33554432   (reused as attn output)
// WT_O    @ 83886080   : 4096x4096 bf16 = 33554432
// QR      @ 134217728  : 2*32*2048*128 bf16 = 33554432
// KR      @ 167772160  : 2*8*2048*128 bf16 = 8388608
// VT      @ 176160768  : 2*8*128*2048 bf16 = 8388608
// TAB     @ 184549376  : 2048*64*2 fp32 = 1048576    -> total 185597952

extern "C" void kernel_launch(void* const* d_in, const int* in_sizes, int n_in,
                              void* d_out, int out_size, void* d_ws, size_t ws_size,
                              hipStream_t stream) {
    const float* x  = (const float*)d_in[0];
    const float* wq = (const float*)d_in[1];
    const float* wk = (const float*)d_in[2];
    const float* wv = (const float*)d_in[3];
    const float* wo = (const float*)d_in[4];
    float* out = (float*)d_out;
    char* ws = (char*)d_ws;

    short* wt_qkv = (short*)(ws + 0);
    short* xb     = (short*)(ws + 50331648);
    short* wt_o   = (short*)(ws + 83886080);
    short* qr     = (short*)(ws + 134217728);
    short* kr     = (short*)(ws + 167772160);
    short* vt     = (short*)(ws + 176160768);
    float* tab    = (float*)(ws + 184549376);

    cast_f32_bf16<<<16384, 256, 0, stream>>>(x, xb, 16777216);
    transpose_cast_qkv<<<dim3(128, 192), 256, 0, stream>>>(wq, wk, wv, wt_qkv);
    rope_tables<<<512, 256, 0, stream>>>(tab);
    gemm_qkv<<<dim3(32, 48), 256, 0, stream>>>(xb, wt_qkv, qr, kr, vt, tab);
    transpose_cast<<<dim3(128, 128), 256, 0, stream>>>(wo, wt_o, 4096, 4096);
    // attn v9: 8-wave, balanced complementary rounds, XCD-affine
    attn_kernel<<<512, 512, 0, stream>>>(qr, kr, vt, xb);
    // WO: gemm_bt (triple-confirmed best WO variant)
    gemm_bt<false><<<dim3(32, 32), 256, 0, stream>>>(xb, wt_o, (void*)out, 4096, 4096);
}

// Round 20
// 529.069 us; speedup vs baseline: 1.0278x; 1.0278x over previous
//
#include <hip/hip_runtime.h>
#include <hip/hip_bf16.h>

typedef __attribute__((ext_vector_type(8))) short short8;
typedef __attribute__((ext_vector_type(4))) float f32x4;
typedef __attribute__((ext_vector_type(16))) float f32x16;

#define GLD16(gp, lp) __builtin_amdgcn_global_load_lds( \
    (const __attribute__((address_space(1))) unsigned int*)(gp), \
    (__attribute__((address_space(3))) unsigned int*)(lp), 16, 0, 0)

static __device__ __forceinline__ float bf2f(unsigned short u) {
    union { unsigned int i; float f; } v; v.i = ((unsigned int)u) << 16; return v.f;
}
static __device__ __forceinline__ short f2bf(float f) {
    union { float f; unsigned int i; } v; v.f = f;
    unsigned int r = v.i + 0x7FFFu + ((v.i >> 16) & 1u);
    return (short)(r >> 16);
}
static __device__ __forceinline__ unsigned int cvtpk(float lo, float hi) {
    unsigned int w;
    asm("v_cvt_pk_bf16_f32 %0, %1, %2" : "=v"(w) : "v"(lo), "v"(hi));
    return w;
}

// ---------------- elementwise cast fp32 -> bf16 ----------------
__global__ void cast_f32_bf16(const float* __restrict__ src, short* __restrict__ dst, int n) {
    int i = (blockIdx.x * 256 + threadIdx.x) * 4;
    if (i >= n) return;
    float4 v = *(const float4*)(src + i);
    short4 o;
    o.x = f2bf(v.x); o.y = f2bf(v.y); o.z = f2bf(v.z); o.w = f2bf(v.w);
    *(short4*)(dst + i) = o;
}

// ---------------- merged transpose+cast for wq/wk/wv -> wt_qkv (6144 x 4096 bf16) ----------------
__global__ void transpose_cast_qkv(const float* __restrict__ wq, const float* __restrict__ wk,
                                   const float* __restrict__ wv, short* __restrict__ dst) {
    __shared__ float tile[32][33];
    int k0 = blockIdx.x * 32;
    int yt = blockIdx.y;
    const float* src;
    int N, n0, rowbase;
    if (yt < 128)      { src = wq; N = 4096; n0 = yt * 32;         rowbase = n0; }
    else if (yt < 160) { src = wk; N = 1024; n0 = (yt - 128) * 32; rowbase = 4096 + n0; }
    else               { src = wv; N = 1024; n0 = (yt - 160) * 32; rowbase = 5120 + n0; }
    int t = threadIdx.x, c = t & 31, r = t >> 5;
#pragma unroll
    for (int p = 0; p < 4; ++p)
        tile[r + p * 8][c] = src[(size_t)(k0 + r + p * 8) * N + n0 + c];
    __syncthreads();
#pragma unroll
    for (int p = 0; p < 4; ++p)
        dst[(size_t)(rowbase + r + p * 8) * 4096 + k0 + c] = f2bf(tile[c][r + p * 8]);
}

// ---------------- transpose+cast: src fp32 (K x N) -> dst bf16 (N x K) ----------------
__global__ void transpose_cast(const float* __restrict__ src, short* __restrict__ dst,
                               int N, int dstStride) {
    __shared__ float tile[32][33];
    int k0 = blockIdx.x * 32, n0 = blockIdx.y * 32;
    int t = threadIdx.x, c = t & 31, r = t >> 5;
#pragma unroll
    for (int p = 0; p < 4; ++p)
        tile[r + p * 8][c] = src[(size_t)(k0 + r + p * 8) * N + n0 + c];
    __syncthreads();
#pragma unroll
    for (int p = 0; p < 4; ++p)
        dst[(size_t)(n0 + r + p * 8) * dstStride + k0 + c] = f2bf(tile[c][r + p * 8]);
}

// ---------------- rope tables: [2048][64] float2 (cos,sin) ----------------
__global__ void rope_tables(float* __restrict__ cs) {
    int i = blockIdx.x * 256 + threadIdx.x;
    int s = i >> 6, d2 = i & 63;
    float inv = expf(-9.210340371976184f * (float)(2 * d2) * (1.0f / 128.0f));
    float ang = (float)s * inv;
    float sn, c;
    sincosf(ang, &sn, &c);
    cs[(size_t)i * 2] = c;
    cs[(size_t)i * 2 + 1] = sn;
}

// ---------------- QKV GEMM 128x128 + FUSED rope/regroup/V-transpose epilogue (frozen) ----------------
__global__ __launch_bounds__(256, 2) void gemm_qkv(const short* __restrict__ A,
                                                   const short* __restrict__ Bt,
                                                   short* __restrict__ Qr,
                                                   short* __restrict__ Kr,
                                                   short* __restrict__ Vt,
                                                   const float* __restrict__ tab) {
    __shared__ short As[128 * 64];
    __shared__ short Bs[128 * 64];
    const int K = 4096;
    const int tid = threadIdx.x;
    const int lane = tid & 63;
    const int wid = tid >> 6;
    const int lr = lane & 15;
    const int lq = lane >> 4;
    const int m0 = blockIdx.x * 128;
    const int n0 = blockIdx.y * 128;
    const int wr = (wid >> 1) * 64;
    const int wc = (wid & 1) * 64;
    f32x4 acc[4][4];
#pragma unroll
    for (int i = 0; i < 4; ++i)
#pragma unroll
        for (int j = 0; j < 4; ++j) acc[i][j] = f32x4{0.f, 0.f, 0.f, 0.f};

    const short* aBase = A + (size_t)m0 * K;
    const short* bBase = Bt + (size_t)n0 * K;

    for (int k0 = 0; k0 < K; k0 += 64) {
#pragma unroll
        for (int j = 0; j < 4; ++j) {
            int c = (wid * 4 + j) * 64 + lane;
            int row = c >> 3;
            int cb = ((c & 7) << 4) ^ ((row & 7) << 4);
            GLD16(aBase + (size_t)row * K + k0 + (cb >> 1), As + (wid * 4 + j) * 512);
            GLD16(bBase + (size_t)row * K + k0 + (cb >> 1), Bs + (wid * 4 + j) * 512);
        }
        __syncthreads();
#pragma unroll
        for (int ks = 0; ks < 2; ++ks) {
            short8 af[4], bfr[4];
#pragma unroll
            for (int mi = 0; mi < 4; ++mi) {
                int row = wr + mi * 16 + lr;
                int cb = (ks * 64 + lq * 16) ^ ((row & 7) << 4);
                af[mi] = *(const short8*)(As + row * 64 + (cb >> 1));
            }
#pragma unroll
            for (int ni = 0; ni < 4; ++ni) {
                int row = wc + ni * 16 + lr;
                int cb = (ks * 64 + lq * 16) ^ ((row & 7) << 4);
                bfr[ni] = *(const short8*)(Bs + row * 64 + (cb >> 1));
            }
#pragma unroll
            for (int mi = 0; mi < 4; ++mi)
#pragma unroll
                for (int ni = 0; ni < 4; ++ni)
                    acc[mi][ni] = __builtin_amdgcn_mfma_f32_16x16x32_bf16(af[mi], bfr[ni], acc[mi][ni], 0, 0, 0);
        }
        __syncthreads();
    }

    const float2* t2 = (const float2*)tab;
    if (n0 < 5120) {
        const bool isQ = (n0 < 4096);
        short* dst = isQ ? Qr : Kr;
        const int nh = isQ ? 32 : 8;
        const int coff = isQ ? 0 : 4096;
        const float sc = isQ ? 0.1275174358f : 1.0f;   // (1/sqrt(128)) * log2(e) for Q
#pragma unroll
        for (int mi = 0; mi < 4; ++mi)
#pragma unroll
            for (int ni = 0; ni < 4; ++ni) {
                int col = n0 + wc + ni * 16 + lr - coff;
                int h = col >> 7;
                int d = col & 127;
                int d2 = d >> 1;
                const bool odd = d & 1;
#pragma unroll
                for (int r = 0; r < 4; ++r) {
                    int row = m0 + wr + mi * 16 + lq * 4 + r;
                    int s = row & 2047;
                    int b = row >> 11;
                    float v = acc[mi][ni][r];
                    float vp = __shfl_xor(v, 1, 64);
                    float2 cs2 = t2[s * 64 + d2];
                    float o = odd ? (v * cs2.x + vp * cs2.y) : (v * cs2.x - vp * cs2.y);
                    dst[((size_t)(b * nh + h) * 2048 + s) * 128 + d] = f2bf(o * sc);
                }
            }
    } else {
#pragma unroll
        for (int mi = 0; mi < 4; ++mi)
#pragma unroll
            for (int ni = 0; ni < 4; ++ni) {
                int col = n0 + wc + ni * 16 + lr - 5120;
                int h = col >> 7;
                int d = col & 127;
                int row0 = m0 + wr + mi * 16 + lq * 4;
                int s0 = row0 & 2047;
                int b = row0 >> 11;
                short4 o4;
                o4.x = f2bf(acc[mi][ni][0]);
                o4.y = f2bf(acc[mi][ni][1]);
                o4.z = f2bf(acc[mi][ni][2]);
                o4.w = f2bf(acc[mi][ni][3]);
                *(short4*)(Vt + (size_t)(b * 8 + h) * 128 * 2048 + (size_t)d * 2048 + s0) = o4;
            }
    }
}

// ---------------- GEMM 128x128 (r3-exact, measured-best WO) ----------------
template<bool BF16OUT>
__global__ __launch_bounds__(256, 2) void gemm_bt(const short* __restrict__ A,
                                                  const short* __restrict__ Bt,
                                                  void* __restrict__ Cv,
                                                  int N, int K) {
    __shared__ short As[128 * 64];
    __shared__ short Bs[128 * 64];
    const int tid = threadIdx.x;
    const int lane = tid & 63;
    const int wid = tid >> 6;
    const int lr = lane & 15;
    const int lq = lane >> 4;
    const int m0 = blockIdx.x * 128;
    const int n0 = blockIdx.y * 128;
    const int wr = (wid >> 1) * 64;
    const int wc = (wid & 1) * 64;
    f32x4 acc[4][4];
#pragma unroll
    for (int i = 0; i < 4; ++i)
#pragma unroll
        for (int j = 0; j < 4; ++j) acc[i][j] = f32x4{0.f, 0.f, 0.f, 0.f};

    const short* aBase = A + (size_t)m0 * K;
    const short* bBase = Bt + (size_t)n0 * K;

    for (int k0 = 0; k0 < K; k0 += 64) {
#pragma unroll
        for (int j = 0; j < 4; ++j) {
            int c = (wid * 4 + j) * 64 + lane;
            int row = c >> 3;
            int cb = ((c & 7) << 4) ^ ((row & 7) << 4);
            GLD16(aBase + (size_t)row * K + k0 + (cb >> 1), As + (wid * 4 + j) * 512);
            GLD16(bBase + (size_t)row * K + k0 + (cb >> 1), Bs + (wid * 4 + j) * 512);
        }
        __syncthreads();
#pragma unroll
        for (int ks = 0; ks < 2; ++ks) {
            short8 af[4], bfr[4];
#pragma unroll
            for (int mi = 0; mi < 4; ++mi) {
                int row = wr + mi * 16 + lr;
                int cb = (ks * 64 + lq * 16) ^ ((row & 7) << 4);
                af[mi] = *(const short8*)(As + row * 64 + (cb >> 1));
            }
#pragma unroll
            for (int ni = 0; ni < 4; ++ni) {
                int row = wc + ni * 16 + lr;
                int cb = (ks * 64 + lq * 16) ^ ((row & 7) << 4);
                bfr[ni] = *(const short8*)(Bs + row * 64 + (cb >> 1));
            }
#pragma unroll
            for (int mi = 0; mi < 4; ++mi)
#pragma unroll
                for (int ni = 0; ni < 4; ++ni)
                    acc[mi][ni] = __builtin_amdgcn_mfma_f32_16x16x32_bf16(af[mi], bfr[ni], acc[mi][ni], 0, 0, 0);
        }
        __syncthreads();
    }
#pragma unroll
    for (int mi = 0; mi < 4; ++mi)
#pragma unroll
        for (int ni = 0; ni < 4; ++ni)
#pragma unroll
            for (int r = 0; r < 4; ++r) {
                int row = m0 + wr + mi * 16 + lq * 4 + r;
                int col = n0 + wc + ni * 16 + lr;
                float v = acc[mi][ni][r];
                if constexpr (BF16OUT) ((short*)Cv)[(size_t)row * N + col] = f2bf(v);
                else                   ((float*)Cv)[(size_t)row * N + col] = v;
            }
}

// ---------------- flash attention v8 (r16-exact, measured-best): 4-wave, balanced, affine, exp2 ----------------
__global__ __launch_bounds__(256, 2) void attn_kernel(const short* __restrict__ Qr,
                                                      const short* __restrict__ Kr,
                                                      const short* __restrict__ Vt,
                                                      short* __restrict__ Out) {
    __shared__ short kv[4 * 8192];   // [buf][Ks 8192 | Vs 8192] shorts
    const int id = blockIdx.x;       // 0..1023
    const int rnd = id >> 8;         // 0..3
    const int low = id & 255;
    const int xcd = low & 7;
    const int slot = low >> 3;       // 0..31
    const int g = xcd + 8 * (slot >> 4);   // KV group 0..15
    const int b = g >> 3;
    const int kvh = g & 7;
    const int s16 = slot & 15;
    const int qh = kvh * 4 + (s16 & 3);
    const int qbase = s16 >> 2;      // 0..3
    int qb;
    if (rnd == 0)      qb = 15 - qbase;
    else if (rnd == 1) qb = qbase;
    else if (rnd == 2) qb = 11 - qbase;
    else               qb = 4 + qbase;
    const int bh = b * 32 + qh;
    const int tid = threadIdx.x;
    const int lane = tid & 63;
    const int w = tid >> 6;
    const int l31 = lane & 31;
    const int hi = lane >> 5;
    const int qg0 = qb * 128 + w * 32;

    const short* qbase_p = Qr + ((size_t)bh * 2048 + qg0 + l31) * 128 + hi * 8;
    short8 qf[8];
#pragma unroll
    for (int ks = 0; ks < 8; ++ks)
        qf[ks] = *(const short8*)(qbase_p + ks * 16);

    const short* kbase = Kr + (size_t)(b * 8 + kvh) * 2048 * 128;
    const short* vbase = Vt + (size_t)(b * 8 + kvh) * 128 * 2048;

    auto stage = [&](int kb, int buf) {
        const int s0 = kb * 64;
        short* Kd = kv + buf * 16384;
        short* Vd = kv + buf * 16384 + 8192;
#pragma unroll
        for (int j = 0; j < 4; ++j) {
            int c = j * 256 + tid;
            int krow = c >> 4;
            int kcol = ((c & 15) ^ (krow & 7)) * 8;
            GLD16(kbase + (size_t)(s0 + krow) * 128 + kcol, Kd + (size_t)c * 8);
            int vrow = c >> 3;
            int vcol = ((c & 7) ^ (vrow & 7)) * 8;
            GLD16(vbase + (size_t)vrow * 2048 + s0 + vcol, Vd + (size_t)c * 8);
        }
    };

    float m_run = -INFINITY, l_run = 0.0f;
    f32x16 oacc[4];
#pragma unroll
    for (int dt = 0; dt < 4; ++dt) oacc[dt] = f32x16{0,0,0,0,0,0,0,0,0,0,0,0,0,0,0,0};

    const int nkb = 2 * qb + 2;
    stage(0, 0);   // prologue

    for (int kb = 0; kb < nkb; ++kb) {
        const int buf = kb & 1;
        const int s0 = kb * 64;
        const short* Ks = kv + buf * 16384;
        const short* Vs = kv + buf * 16384 + 8192;

        if (kb + 1 < nkb) {
            stage(kb + 1, buf ^ 1);
            __builtin_amdgcn_sched_barrier(0);
            asm volatile("s_waitcnt vmcnt(8)" ::: "memory");   // stage(kb) landed; prefetch in flight
        } else {
            asm volatile("s_waitcnt vmcnt(0)" ::: "memory");
        }
        __builtin_amdgcn_sched_barrier(0);
        __builtin_amdgcn_s_barrier();
        __builtin_amdgcn_sched_barrier(0);

        if (s0 <= qg0 + 31) {
            f32x16 st0 = f32x16{0,0,0,0,0,0,0,0,0,0,0,0,0,0,0,0};
            f32x16 st1 = f32x16{0,0,0,0,0,0,0,0,0,0,0,0,0,0,0,0};
            __builtin_amdgcn_s_setprio(1);
#pragma unroll
            for (int ks = 0; ks < 8; ++ks) {
                int row0 = l31;
                int ch0 = ((2 * ks + hi) ^ (row0 & 7)) * 8;
                short8 kf0 = *(const short8*)(Ks + row0 * 128 + ch0);
                st0 = __builtin_amdgcn_mfma_f32_32x32x16_bf16(kf0, qf[ks], st0, 0, 0, 0);
                int row1 = 32 + l31;
                int ch1 = ((2 * ks + hi) ^ (row1 & 7)) * 8;
                short8 kf1 = *(const short8*)(Ks + row1 * 128 + ch1);
                st1 = __builtin_amdgcn_mfma_f32_32x32x16_bf16(kf1, qf[ks], st1, 0, 0, 0);
            }
            __builtin_amdgcn_s_setprio(0);

            const int q = qg0 + l31;
            if (s0 + 63 > qg0) {
#pragma unroll
                for (int i = 0; i < 16; ++i) {
                    int kvr = (i & 3) + 8 * (i >> 2) + 4 * hi;
                    if (s0 + kvr > q)      st0[i] = -INFINITY;
                    if (s0 + 32 + kvr > q) st1[i] = -INFINITY;
                }
            }

            float mx = -INFINITY;
#pragma unroll
            for (int i = 0; i < 16; ++i) mx = fmaxf(mx, fmaxf(st0[i], st1[i]));
            mx = fmaxf(mx, __shfl_xor(mx, 32, 64));

            const bool defer = __all(mx - m_run <= 11.5415603f);   // 8 * log2(e)
            float mN, alpha;
            if (defer) { mN = m_run; alpha = 1.0f; }
            else       { mN = fmaxf(m_run, mx); alpha = exp2f(m_run - mN); }

            float p0[16], p1[16];
            float rsum = 0.0f;
#pragma unroll
            for (int i = 0; i < 16; ++i) {
                p0[i] = exp2f(st0[i] - mN);
                p1[i] = exp2f(st1[i] - mN);
                rsum += p0[i] + p1[i];
            }
            rsum += __shfl_xor(rsum, 32, 64);
            l_run = l_run * alpha + rsum;
            m_run = mN;
            if (!defer) {
#pragma unroll
                for (int dt = 0; dt < 4; ++dt)
#pragma unroll
                    for (int i = 0; i < 16; ++i) oacc[dt][i] *= alpha;
            }

            short8 pfr[4];
#pragma unroll
            for (int kvs = 0; kvs < 4; ++kvs) {
                const float* pp = (kvs < 2) ? p0 : p1;
                const int h8 = (kvs & 1) * 8;
                unsigned int x0 = cvtpk(pp[h8 + 0], pp[h8 + 1]);
                unsigned int x1 = cvtpk(pp[h8 + 2], pp[h8 + 3]);
                unsigned int y0 = cvtpk(pp[h8 + 4], pp[h8 + 5]);
                unsigned int y1 = cvtpk(pp[h8 + 6], pp[h8 + 7]);
                asm("v_permlane32_swap_b32 %0, %1" : "+v"(x0), "+v"(y0));
                asm("v_permlane32_swap_b32 %0, %1" : "+v"(x1), "+v"(y1));
                union { unsigned int u[4]; short8 s; } uu;
                uu.u[0] = x0; uu.u[1] = x1; uu.u[2] = y0; uu.u[3] = y1;
                pfr[kvs] = uu.s;
            }

            __builtin_amdgcn_s_setprio(1);
#pragma unroll
            for (int dt = 0; dt < 4; ++dt) {
                int row = dt * 32 + l31;
#pragma unroll
                for (int kvs = 0; kvs < 4; ++kvs) {
                    int ch = ((2 * kvs + hi) ^ (row & 7)) * 8;
                    short8 vf = *(const short8*)(Vs + row * 64 + ch);
                    oacc[dt] = __builtin_amdgcn_mfma_f32_32x32x16_bf16(vf, pfr[kvs], oacc[dt], 0, 0, 0);
                }
            }
            __builtin_amdgcn_s_setprio(0);
        }
        __builtin_amdgcn_sched_barrier(0);
        __builtin_amdgcn_s_barrier();
        __builtin_amdgcn_sched_barrier(0);
    }

    const float inv = 1.0f / l_run;
    const size_t row = (size_t)b * 2048 + qg0 + l31;
    short* obase = Out + row * 4096 + qh * 128;
#pragma unroll
    for (int dt = 0; dt < 4; ++dt) {
#pragma unroll
        for (int g2 = 0; g2 < 4; ++g2) {
            short4 o4;
            o4.x = f2bf(oacc[dt][g2 * 4 + 0] * inv);
            o4.y = f2bf(oacc[dt][g2 * 4 + 1] * inv);
            o4.z = f2bf(oacc[dt][g2 * 4 + 2] * inv);
            o4.w = f2bf(oacc[dt][g2 * 4 + 3] * inv);
            *(short4*)(obase + dt * 32 + g2 * 8 + hi * 4) = o4;
        }
    }
}

// ---------------- workspace layout (bytes) ----------------
// WT_QKV  @ 0          : 6144x4096 bf16 = 50331648
// XB      @ 50331648   : 4096x4096 bf16 = 33554432   (reused as attn output)
// WT_O    @ 83886080   : 4096x4096 bf16 = 33554432
// QR      @ 134217728  : 2*32*2048*128 bf16 = 33554432
// KR      @ 167772160  : 2*8*2048*128 bf16 = 8388608
// VT      @ 176160768  : 2*8*128*2048 bf16 = 8388608
// TAB     @ 184549376  : 2048*64*2 fp32 = 1048576    -> total 185597952

extern "C" void kernel_launch(void* const* d_in, const int* in_sizes, int n_in,
                              void* d_out, int out_size, void* d_ws, size_t ws_size,
                              hipStream_t stream) {
    const float* x  = (const float*)d_in[0];
    const float* wq = (const float*)d_in[1];
    const float* wk = (const float*)d_in[2];
    const float* wv = (const float*)d_in[3];
    const float* wo = (const float*)d_in[4];
    float* out = (float*)d_out;
    char* ws = (char*)d_ws;

    short* wt_qkv = (short*)(ws + 0);
    short* xb     = (short*)(ws + 50331648);
    short* wt_o   = (short*)(ws + 83886080);
    short* qr     = (short*)(ws + 134217728);
    short* kr     = (short*)(ws + 167772160);
    short* vt     = (short*)(ws + 176160768);
    float* tab    = (float*)(ws + 184549376);

    cast_f32_bf16<<<16384, 256, 0, stream>>>(x, xb, 16777216);
    transpose_cast_qkv<<<dim3(128, 192), 256, 0, stream>>>(wq, wk, wv, wt_qkv);
    rope_tables<<<512, 256, 0, stream>>>(tab);
    gemm_qkv<<<dim3(32, 48), 256, 0, stream>>>(xb, wt_qkv, qr, kr, vt, tab);
    transpose_cast<<<dim3(128, 128), 256, 0, stream>>>(wo, wt_o, 4096, 4096);
    // attn v8 (r16-exact): 4-wave, balanced complementary-qb, XCD-affine
    attn_kernel<<<1024, 256, 0, stream>>>(qr, kr, vt, xb);
    // WO: gemm_bt (measured-best WO variant across r16/r17/r18)
    gemm_bt<false><<<dim3(32, 32), 256, 0, stream>>>(xb, wt_o, (void*)out, 4096, 4096);
}